// Round 1
// baseline (372.316 us; speedup 1.0000x reference)
//
#include <hip/hip_runtime.h>
#include <math.h>

#define BB 16
#define SS 512
#define DD 128
#define HH 8
#define NCONV 4
#define KW 7
#define DKK 16
#define NN (BB*SS)   // 8192 rows
#define LN_EPS 1e-5f

// -------------------- positional encoding add --------------------
__global__ __launch_bounds__(128) void pos_add_kernel(const float* __restrict__ x,
                                                      float* __restrict__ out) {
  int r = blockIdx.x;
  int d = threadIdx.x;
  int s = r & (SS - 1);
  const float inc = 0.14619588f;  // log(10000)/63
  int c = d & 63;
  float invf = __expf(-inc * (float)c);
  float st = (float)s * invf;
  float p = (d < 64) ? sinf(st) : cosf(st);
  out[r*DD + d] = x[r*DD + d] + p;
}

// -------------------- layernorm (one row / 128-thread block) --------------------
__global__ __launch_bounds__(128) void ln_kernel(const float* __restrict__ in,
    const float* __restrict__ g, const float* __restrict__ b, float* __restrict__ out) {
  int r = blockIdx.x, d = threadIdx.x;
  float v = in[r*DD + d];
  float s1 = v, s2 = v*v;
  #pragma unroll
  for (int o = 32; o > 0; o >>= 1) {
    s1 += __shfl_xor(s1, o, 64);
    s2 += __shfl_xor(s2, o, 64);
  }
  __shared__ float sh[4];
  if ((d & 63) == 0) { sh[(d>>6)*2] = s1; sh[(d>>6)*2+1] = s2; }
  __syncthreads();
  float t1 = sh[0] + sh[2], t2 = sh[1] + sh[3];
  float mu  = t1 * (1.0f/DD);
  float var = t2 * (1.0f/DD) - mu*mu;
  float inv = rsqrtf(var + LN_EPS);
  out[r*DD + d] = (v - mu) * inv * g[d] + b[d];
}

// -------------------- depthwise conv along S (k=7, pad=3) + bias --------------------
__global__ __launch_bounds__(128) void dwconv_kernel(const float* __restrict__ h,
    const float* __restrict__ w, const float* __restrict__ bias, float* __restrict__ y) {
  int r = blockIdx.x, d = threadIdx.x;
  int s = r & (SS - 1);
  float acc = bias[d];
  #pragma unroll
  for (int k = 0; k < KW; ++k) {
    int ss = s + k - 3;
    float hv = (ss >= 0 && ss < SS) ? h[(r + k - 3)*DD + d] : 0.0f;
    acc += hv * w[d*KW + k];
  }
  y[r*DD + d] = acc;
}

// -------------------- generic fused matmul --------------------
// out[r, ob+o] = act( sum_i in[r,i] * W[(ob+o)*128 + i] + bias ) (+ res[r, ob+o])
// block: 256 threads -> 32 rows x 128 outs. W row-major [O,128].
// LDS stride 130 floats -> float2 reads land as 2-way bank aliasing (free).
template<int ACT, int BIASMODE, int RES>
__global__ __launch_bounds__(256) void mm_kernel(const float* __restrict__ in,
    const float* __restrict__ W, const float* __restrict__ bias,
    const float* res, float* out, int ostride) {
  __shared__ float sW[128*130];
  __shared__ float sIn[32*130];
  int t  = threadIdx.x;
  int r0 = blockIdx.x * 32;
  int ob = blockIdx.y * 128;
  for (int idx = t; idx < 128*128; idx += 256) {
    int row = idx >> 7, col = idx & 127;
    sW[row*130 + col] = W[(ob + row)*128 + col];
  }
  for (int idx = t; idx < 32*128; idx += 256) {
    int row = idx >> 7, col = idx & 127;
    sIn[row*130 + col] = in[(r0 + row)*128 + col];
  }
  __syncthreads();
  int rg = t & 7;    // 8 row-groups of 4 rows (lane&7 -> conflict-free broadcast)
  int og = t >> 3;   // 32 out-groups of 4 outs
  float acc[4][4];
  #pragma unroll
  for (int j = 0; j < 4; ++j)
    #pragma unroll
    for (int k = 0; k < 4; ++k) acc[j][k] = 0.0f;
  const float* pI = sIn + rg*4*130;
  const float* pW = sW  + og*4*130;
  #pragma unroll 4
  for (int i = 0; i < 128; i += 2) {
    float2 a[4], w[4];
    #pragma unroll
    for (int j = 0; j < 4; ++j) a[j] = *(const float2*)(pI + j*130 + i);
    #pragma unroll
    for (int k = 0; k < 4; ++k) w[k] = *(const float2*)(pW + k*130 + i);
    #pragma unroll
    for (int j = 0; j < 4; ++j)
      #pragma unroll
      for (int k = 0; k < 4; ++k)
        acc[j][k] += a[j].x * w[k].x + a[j].y * w[k].y;
  }
  float bv[4];
  #pragma unroll
  for (int k = 0; k < 4; ++k)
    bv[k] = (BIASMODE == 1) ? bias[ob + og*4 + k] : ((BIASMODE == 2) ? bias[0] : 0.0f);
  #pragma unroll
  for (int j = 0; j < 4; ++j) {
    int r = r0 + rg*4 + j;
    int o = ob + og*4;
    float4 v;
    v.x = acc[j][0] + bv[0];
    v.y = acc[j][1] + bv[1];
    v.z = acc[j][2] + bv[2];
    v.w = acc[j][3] + bv[3];
    if (ACT == 1) {
      v.x = fmaxf(v.x, 0.0f); v.y = fmaxf(v.y, 0.0f);
      v.z = fmaxf(v.z, 0.0f); v.w = fmaxf(v.w, 0.0f);
    }
    if (RES) {
      const float4 rr = *(const float4*)(res + r*DD + o);
      v.x += rr.x; v.y += rr.y; v.z += rr.z; v.w += rr.w;
    }
    *(float4*)(out + r*ostride + o) = v;
  }
}

// -------------------- attention core --------------------
// grid: (B*H*2) blocks, 256 threads; each thread = 1 query row.
// qkv layout: [N, 384] (q:0-127, k:128-255, v:256-383), head h at h*16.
// No max-subtraction: |scores| <= ~25 -> exp safe in fp32, same softmax result.
__global__ __launch_bounds__(256) void attn_kernel(const float* __restrict__ qkv,
    const int* __restrict__ mask, float* __restrict__ att) {
  __shared__ float sK[SS*DKK];   // 32 KB
  __shared__ float sV[SS*DKK];   // 32 KB
  __shared__ float sM[SS];
  int blk = blockIdx.x;
  int scn = blk & 1;
  int h   = (blk >> 1) & (HH - 1);
  int b   = blk >> 4;
  int t   = threadIdx.x;
  for (int idx = t; idx < SS*DKK; idx += 256) {
    int s = idx >> 4, kk = idx & 15;
    int base = (b*SS + s)*384 + h*DKK + kk;
    sK[idx] = qkv[base + 128];
    sV[idx] = qkv[base + 256];
  }
  for (int idx = t; idx < SS; idx += 256) sM[idx] = (float)mask[b*SS + idx];
  __syncthreads();
  int qs = scn*256 + t;
  float q[DKK];
  #pragma unroll
  for (int kk = 0; kk < DKK; ++kk)
    q[kk] = qkv[(b*SS + qs)*384 + h*DKK + kk] * 0.25f;   // 1/sqrt(dk)
  float l = 0.0f;
  float acc[DKK];
  #pragma unroll
  for (int kk = 0; kk < DKK; ++kk) acc[kk] = 0.0f;
  for (int tk = 0; tk < SS; ++tk) {
    float scv = 0.0f;
    #pragma unroll
    for (int kk = 0; kk < DKK; ++kk) scv += q[kk] * sK[tk*DKK + kk];
    float e = __expf(scv) * sM[tk];
    l += e;
    #pragma unroll
    for (int kk = 0; kk < DKK; ++kk) acc[kk] += e * sV[tk*DKK + kk];
  }
  float invl = 1.0f / l;
  #pragma unroll
  for (int kk = 0; kk < DKK; ++kk)
    att[(b*SS + qs)*DD + h*DKK + kk] = acc[kk] * invl;
}

// -------------------- weight repacks (run every call; ws is re-poisoned) --------------------
__global__ __launch_bounds__(256) void repack_wqkv_kernel(const float* __restrict__ Wq,
    const float* __restrict__ Wk, const float* __restrict__ Wv, float* __restrict__ dst) {
  int idx = blockIdx.x * 256 + threadIdx.x;  // 49152 total
  int which = idx >> 14;
  int rem = idx & 16383;
  int o = rem >> 7, d = rem & 127;
  int h = o >> 4, kk = o & 15;
  const float* src = (which == 0) ? Wq : ((which == 1) ? Wk : Wv);
  dst[idx] = src[h*(DD*DKK) + d*DKK + kk];
}

__global__ __launch_bounds__(256) void transpose_wo_kernel(const float* __restrict__ Wo,
                                                           float* __restrict__ dst) {
  int idx = blockIdx.x * 256 + threadIdx.x;  // 16384
  int o = idx >> 7, i = idx & 127;
  dst[idx] = Wo[i*DD + o];
}

// -------------------- driver --------------------
extern "C" void kernel_launch(void* const* d_in, const int* in_sizes, int n_in,
                              void* d_out, int out_size, void* d_ws, size_t ws_size,
                              hipStream_t stream) {
  const float* x        = (const float*)d_in[0];
  const int*   mask     = (const int*)d_in[1];
  const float* ln_scale = (const float*)d_in[2];
  const float* ln_bias  = (const float*)d_in[3];
  const float* dw_w     = (const float*)d_in[4];
  const float* dw_b     = (const float*)d_in[5];
  const float* pw_w     = (const float*)d_in[6];
  const float* pw_b     = (const float*)d_in[7];
  const float* Wq       = (const float*)d_in[8];
  const float* Wk       = (const float*)d_in[9];
  const float* Wv       = (const float*)d_in[10];
  const float* Wo       = (const float*)d_in[11];
  const float* att_bias = (const float*)d_in[12];
  const float* f1_w     = (const float*)d_in[13];
  const float* f1_b     = (const float*)d_in[14];
  const float* f2_w     = (const float*)d_in[15];
  const float* f2_b     = (const float*)d_in[16];

  float* out = (float*)d_out;
  float* wsf = (float*)d_ws;
  float* ws_h    = wsf;                                        // N*D
  float* ws_y    = wsf + (size_t)NN*DD;                        // N*D
  float* ws_qkv  = wsf + (size_t)2*NN*DD;                      // N*384
  float* ws_att  = wsf + (size_t)2*NN*DD + (size_t)NN*384;     // N*D
  float* ws_wqkv = ws_att + (size_t)NN*DD;                     // 384*128
  float* ws_wo   = ws_wqkv + 384*128;                          // 128*128

  hipLaunchKernelGGL(repack_wqkv_kernel, dim3(192), dim3(256), 0, stream, Wq, Wk, Wv, ws_wqkv);
  hipLaunchKernelGGL(transpose_wo_kernel, dim3(64), dim3(256), 0, stream, Wo, ws_wo);

  hipLaunchKernelGGL(pos_add_kernel, dim3(NN), dim3(128), 0, stream, x, out);

  for (int i = 0; i < NCONV; ++i) {
    hipLaunchKernelGGL(ln_kernel, dim3(NN), dim3(128), 0, stream,
                       out, ln_scale + i*DD, ln_bias + i*DD, ws_h);
    hipLaunchKernelGGL(dwconv_kernel, dim3(NN), dim3(128), 0, stream,
                       ws_h, dw_w + i*DD*KW, dw_b + i*DD, ws_y);
    // pointwise conv: relu(W*y + b) + residual(out)
    hipLaunchKernelGGL((mm_kernel<1,1,1>), dim3(NN/32, 1), dim3(256), 0, stream,
                       ws_y, pw_w + i*DD*DD, pw_b + i*DD, out, out, DD);
  }

  // attention
  hipLaunchKernelGGL(ln_kernel, dim3(NN), dim3(128), 0, stream,
                     out, ln_scale + 4*DD, ln_bias + 4*DD, ws_h);
  hipLaunchKernelGGL((mm_kernel<0,2,0>), dim3(NN/32, 3), dim3(256), 0, stream,
                     ws_h, ws_wqkv, att_bias, nullptr, ws_qkv, 384);
  hipLaunchKernelGGL(attn_kernel, dim3(BB*HH*2), dim3(256), 0, stream,
                     ws_qkv, mask, ws_att);
  hipLaunchKernelGGL((mm_kernel<0,2,1>), dim3(NN/32, 1), dim3(256), 0, stream,
                     ws_att, ws_wo, att_bias, out, out, DD);

  // feed-forward
  hipLaunchKernelGGL(ln_kernel, dim3(NN), dim3(128), 0, stream,
                     out, ln_scale + 5*DD, ln_bias + 5*DD, ws_h);
  hipLaunchKernelGGL((mm_kernel<1,1,0>), dim3(NN/32, 1), dim3(256), 0, stream,
                     ws_h, f1_w, f1_b, nullptr, ws_y, DD);
  hipLaunchKernelGGL((mm_kernel<0,1,1>), dim3(NN/32, 1), dim3(256), 0, stream,
                     ws_y, f2_w, f2_b, out, out, DD);
}

// Round 2
// 176.182 us; speedup vs baseline: 2.1132x; 2.1132x over previous
//
#include <hip/hip_runtime.h>
#include <math.h>

#define BB 16
#define SS 512
#define DD 128
#define HH 8
#define NCONV 4
#define KW 7
#define DKK 16
#define NN (BB*SS)   // 8192 rows
#define LN_EPS 1e-5f

typedef __attribute__((ext_vector_type(8))) short short8;
typedef __attribute__((ext_vector_type(4))) short short4v;
typedef __attribute__((ext_vector_type(4))) float f4;

static __device__ __forceinline__ ushort f2bf(float x) {
  union { float f; unsigned u; } v; v.f = x;
  unsigned r = v.u + 0x7fffu + ((v.u >> 16) & 1u);
  return (ushort)(r >> 16);
}

static __device__ __forceinline__ float posenc(int s, int col) {
  const float inc = 0.14619588f;               // log(10000)/63
  int c = col & 63;
  float invf = expf(-inc * (float)c);
  float st = (float)s * invf;
  return (col < 64) ? sinf(st) : cosf(st);
}

// ==================== weight prep: cast/pack everything to bf16 ====================
// dst layout (ushort): [0:65536) pw (4 layers, [o][d]); [65536:114688) wqkv [o(384)][d];
// [114688:131072) wo^T [o][d]; [131072:147456) f1 [o][d]; [147456:163840) f2 [o][d]
__global__ __launch_bounds__(256) void prep_kernel(
    const float* __restrict__ pw, const float* __restrict__ Wq,
    const float* __restrict__ Wk, const float* __restrict__ Wv,
    const float* __restrict__ Wo, const float* __restrict__ f1,
    const float* __restrict__ f2, ushort* __restrict__ dst) {
  int i = blockIdx.x * 256 + threadIdx.x;
  if (i < 65536) { dst[i] = f2bf(pw[i]); return; }
  int j = i - 65536;
  if (j < 49152) {
    int o = j >> 7, d = j & 127;
    int sec = o >> 7, oo = o & 127, hh = oo >> 4, kk = oo & 15;
    const float* s = (sec == 0) ? Wq : ((sec == 1) ? Wk : Wv);
    dst[i] = f2bf(s[hh*2048 + d*16 + kk]); return;
  }
  j -= 49152;
  if (j < 16384) { int o = j >> 7, d = j & 127; dst[i] = f2bf(Wo[d*128 + o]); return; }
  j -= 16384;
  if (j < 16384) { dst[i] = f2bf(f1[j]); return; }
  j -= 16384;
  dst[i] = f2bf(f2[j]);
}

// ==================== generic fused [LN+] matmul (M=16 rows/block, MFMA) ====================
// grid.x = NN/16, grid.y = col-chunks of 128. W bf16 [O][128] row-major.
template<int LNORM, int ACT, int BIASMODE, int RES, int OUTBF>
__global__ __launch_bounds__(256) void mm16_kernel(
    const float* __restrict__ in_f, const ushort* __restrict__ in_b,
    const ushort* __restrict__ Wb,
    const float* __restrict__ gamma, const float* __restrict__ beta,
    const float* __restrict__ bias, const float* __restrict__ res,
    float* __restrict__ out_f, ushort* __restrict__ out_b, int ostride) {
  __shared__ ushort abuf[16*152];
  __shared__ ushort wbuf[128*152];
  int t = threadIdx.x;
  int r0 = blockIdx.x * 16;
  int ocol0 = blockIdx.y * 128;
  const ushort* W = Wb + blockIdx.y * (128*128);

  for (int i = t; i < 128*16; i += 256) {           // stage weights
    int row = i >> 4, ch = i & 15;
    *(short8*)&wbuf[row*152 + ch*8] = *(const short8*)&W[row*128 + ch*8];
  }
  int wv = t >> 6, lane = t & 63;
  if (LNORM) {
    for (int i = wv; i < 16; i += 4) {
      int r = r0 + i;
      float2 xv = *(const float2*)&in_f[r*128 + lane*2];
      float s1 = xv.x + xv.y, s2 = xv.x*xv.x + xv.y*xv.y;
      #pragma unroll
      for (int o = 32; o > 0; o >>= 1) { s1 += __shfl_xor(s1, o); s2 += __shfl_xor(s2, o); }
      float mu = s1 * (1.0f/128.0f);
      float var = s2 * (1.0f/128.0f) - mu*mu;
      float inv = rsqrtf(var + LN_EPS);
      float2 gv = *(const float2*)&gamma[lane*2];
      float2 bv = *(const float2*)&beta[lane*2];
      float n0 = (xv.x - mu)*inv*gv.x + bv.x;
      float n1 = (xv.y - mu)*inv*gv.y + bv.y;
      unsigned pk = (unsigned)f2bf(n0) | ((unsigned)f2bf(n1) << 16);
      *(unsigned*)&abuf[i*152 + lane*2] = pk;
    }
  } else {
    for (int i = t; i < 16*16; i += 256) {
      int row = i >> 4, ch = i & 15;
      *(short8*)&abuf[row*152 + ch*8] = *(const short8*)&in_b[(r0+row)*128 + ch*8];
    }
  }
  __syncthreads();

  int m = lane & 15, qd = lane >> 4;
  int c0 = wv * 32;
  f4 acc0 = {0.f,0.f,0.f,0.f}, acc1 = {0.f,0.f,0.f,0.f};
  #pragma unroll
  for (int ks = 0; ks < 4; ++ks) {
    short8 a  = *(const short8*)&abuf[m*152 + ks*32 + qd*8];
    short8 b0 = *(const short8*)&wbuf[(c0 + m)*152 + ks*32 + qd*8];
    short8 b1 = *(const short8*)&wbuf[(c0 + 16 + m)*152 + ks*32 + qd*8];
    acc0 = __builtin_amdgcn_mfma_f32_16x16x32_bf16(a, b0, acc0, 0, 0, 0);
    acc1 = __builtin_amdgcn_mfma_f32_16x16x32_bf16(a, b1, acc1, 0, 0, 0);
  }
  int col0 = c0 + m, col1 = c0 + 16 + m;
  float bv0 = (BIASMODE==1) ? bias[col0] : ((BIASMODE==2) ? bias[0] : 0.0f);
  float bv1 = (BIASMODE==1) ? bias[col1] : ((BIASMODE==2) ? bias[0] : 0.0f);
  #pragma unroll
  for (int reg = 0; reg < 4; ++reg) {
    int r = r0 + qd*4 + reg;
    float v0 = acc0[reg] + bv0, v1 = acc1[reg] + bv1;
    if (ACT) { v0 = fmaxf(v0, 0.0f); v1 = fmaxf(v1, 0.0f); }
    if (RES) { v0 += res[r*128 + col0]; v1 += res[r*128 + col1]; }
    if (OUTBF) {
      out_b[r*ostride + ocol0 + col0] = f2bf(v0);
      out_b[r*ostride + ocol0 + col1] = f2bf(v1);
    } else {
      out_f[r*ostride + ocol0 + col0] = v0;
      out_f[r*ostride + ocol0 + col1] = v1;
    }
  }
}

// ==================== fused conv layer: LN + dwconv(k=7) + pointwise MFMA + relu + res ====================
template<int ADDPOS>
__global__ __launch_bounds__(256) void conv_fused_kernel(
    const float* __restrict__ cur, const ushort* __restrict__ pwW,
    const float* __restrict__ gamma, const float* __restrict__ beta,
    const float* __restrict__ dww, const float* __restrict__ dwb,
    const float* __restrict__ pwb, float* __restrict__ out) {
  __shared__ float  hbuf[22*128];
  __shared__ ushort ybuf[16*152];
  __shared__ ushort wbuf[128*152];
  int t = threadIdx.x;
  int r0 = blockIdx.x * 16;
  int s0 = r0 & (SS-1);
  int bb = r0 >> 9;

  for (int i = t; i < 128*16; i += 256) {
    int row = i >> 4, ch = i & 15;
    *(short8*)&wbuf[row*152 + ch*8] = *(const short8*)&pwW[row*128 + ch*8];
  }
  int wv = t >> 6, lane = t & 63;
  for (int i = wv; i < 22; i += 4) {               // LN rows s0-3 .. s0+18 (halo)
    int s = s0 - 3 + i;
    if (s < 0 || s >= SS) {
      *(float2*)&hbuf[i*128 + lane*2] = make_float2(0.f, 0.f);
      continue;
    }
    int r = bb*SS + s;
    float2 xv = *(const float2*)&cur[r*128 + lane*2];
    if (ADDPOS) { xv.x += posenc(s, lane*2); xv.y += posenc(s, lane*2+1); }
    float s1 = xv.x + xv.y, s2 = xv.x*xv.x + xv.y*xv.y;
    #pragma unroll
    for (int o = 32; o > 0; o >>= 1) { s1 += __shfl_xor(s1, o); s2 += __shfl_xor(s2, o); }
    float mu = s1 * (1.0f/128.0f);
    float var = s2 * (1.0f/128.0f) - mu*mu;
    float inv = rsqrtf(var + LN_EPS);
    float2 gv = *(const float2*)&gamma[lane*2];
    float2 bv = *(const float2*)&beta[lane*2];
    hbuf[i*128 + lane*2]     = (xv.x - mu)*inv*gv.x + bv.x;
    hbuf[i*128 + lane*2 + 1] = (xv.y - mu)*inv*gv.y + bv.y;
  }
  __syncthreads();

  {                                                // depthwise conv
    int col = t & 127, rg = t >> 7;
    float w0 = dww[col*7+0], w1 = dww[col*7+1], w2 = dww[col*7+2], w3 = dww[col*7+3];
    float w4 = dww[col*7+4], w5 = dww[col*7+5], w6 = dww[col*7+6];
    float bs = dwb[col];
    #pragma unroll
    for (int rr = rg*8; rr < rg*8 + 8; ++rr) {
      float acc = bs;
      acc += hbuf[(rr+0)*128 + col] * w0;
      acc += hbuf[(rr+1)*128 + col] * w1;
      acc += hbuf[(rr+2)*128 + col] * w2;
      acc += hbuf[(rr+3)*128 + col] * w3;
      acc += hbuf[(rr+4)*128 + col] * w4;
      acc += hbuf[(rr+5)*128 + col] * w5;
      acc += hbuf[(rr+6)*128 + col] * w6;
      ybuf[rr*152 + col] = f2bf(acc);
    }
  }
  __syncthreads();

  int m = lane & 15, qd = lane >> 4;
  int c0 = wv * 32;
  f4 acc0 = {0.f,0.f,0.f,0.f}, acc1 = {0.f,0.f,0.f,0.f};
  #pragma unroll
  for (int ks = 0; ks < 4; ++ks) {
    short8 a  = *(const short8*)&ybuf[m*152 + ks*32 + qd*8];
    short8 b0 = *(const short8*)&wbuf[(c0 + m)*152 + ks*32 + qd*8];
    short8 b1 = *(const short8*)&wbuf[(c0 + 16 + m)*152 + ks*32 + qd*8];
    acc0 = __builtin_amdgcn_mfma_f32_16x16x32_bf16(a, b0, acc0, 0, 0, 0);
    acc1 = __builtin_amdgcn_mfma_f32_16x16x32_bf16(a, b1, acc1, 0, 0, 0);
  }
  int col0 = c0 + m, col1 = c0 + 16 + m;
  float bv0 = pwb[col0], bv1 = pwb[col1];
  #pragma unroll
  for (int reg = 0; reg < 4; ++reg) {
    int r = r0 + qd*4 + reg;
    int s = s0 + qd*4 + reg;
    float v0 = fmaxf(acc0[reg] + bv0, 0.0f);
    float v1 = fmaxf(acc1[reg] + bv1, 0.0f);
    float rz0 = cur[r*128 + col0], rz1 = cur[r*128 + col1];
    if (ADDPOS) { rz0 += posenc(s, col0); rz1 += posenc(s, col1); }
    out[r*128 + col0] = v0 + rz0;
    out[r*128 + col1] = v1 + rz1;
  }
}

// ==================== MFMA attention ====================
// grid = B*H*8 (Q-chunks of 64 rows), 256 thr (4 waves, 16 Q-rows each).
// qkv bf16 [N][384] (q|k|v, head h at h*16). No max-subtraction (scores bounded).
__global__ __launch_bounds__(256) void attn_mfma_kernel(
    const ushort* __restrict__ qkv, const int* __restrict__ mask,
    ushort* __restrict__ att) {
  __shared__ ushort kbuf[512*24];    // K rows, stride 24 (b128-aligned, 2-way banks)
  __shared__ ushort vbuf[512*20];    // V rows, stride 20
  __shared__ ushort pbuf[4*16*40];   // per-wave P tile [16][40]
  __shared__ float  smask[512];
  int t = threadIdx.x;
  int blk = blockIdx.x;
  int qc = blk & 7, h = (blk >> 3) & 7, b = blk >> 6;

  for (int i = t; i < 512; i += 256) smask[i] = (float)mask[b*SS + i];
  for (int i = t; i < 1024; i += 256) {
    int s = i >> 1, half = i & 1;
    *(short8*)&kbuf[s*24 + half*8] =
      *(const short8*)&qkv[(size_t)(b*SS + s)*384 + 128 + h*16 + half*8];
  }
  for (int i = t; i < 2048; i += 256) {
    int s = i >> 2, qu = i & 3;
    *(short4v*)&vbuf[s*20 + qu*4] =
      *(const short4v*)&qkv[(size_t)(b*SS + s)*384 + 256 + h*16 + qu*4];
  }
  __syncthreads();

  int wv = t >> 6, lane = t & 63;
  int m = lane & 15, qd = lane >> 4;
  int qr0 = qc*64 + wv*16;

  short8 aq = (short8)0;
  if (qd < 2) aq = *(const short8*)&qkv[(size_t)(b*SS + qr0 + m)*384 + h*16 + qd*8];

  f4 oacc = {0.f,0.f,0.f,0.f};
  float lp0 = 0.f, lp1 = 0.f, lp2 = 0.f, lp3 = 0.f;
  ushort* pb = &pbuf[wv*640];
  f4 zz = {0.f,0.f,0.f,0.f};

  for (int step = 0; step < 16; ++step) {
    int kb = step * 32;
    short8 bk0 = (short8)0, bk1 = (short8)0;
    if (qd < 2) {
      bk0 = *(const short8*)&kbuf[(kb + m)*24 + qd*8];
      bk1 = *(const short8*)&kbuf[(kb + 16 + m)*24 + qd*8];
    }
    f4 s0 = __builtin_amdgcn_mfma_f32_16x16x32_bf16(aq, bk0, zz, 0, 0, 0);
    f4 s1 = __builtin_amdgcn_mfma_f32_16x16x32_bf16(aq, bk1, zz, 0, 0, 0);
    float mk0 = smask[kb + m], mk1 = smask[kb + 16 + m];
    #pragma unroll
    for (int reg = 0; reg < 4; ++reg) {
      float e0 = __expf(s0[reg] * 0.25f) * mk0;
      float e1 = __expf(s1[reg] * 0.25f) * mk1;
      if (reg == 0) { lp0 += e0 + e1; } else if (reg == 1) { lp1 += e0 + e1; }
      else if (reg == 2) { lp2 += e0 + e1; } else { lp3 += e0 + e1; }
      pb[(qd*4 + reg)*40 + m]      = f2bf(e0);
      pb[(qd*4 + reg)*40 + 16 + m] = f2bf(e1);
    }
    __asm__ volatile("s_waitcnt lgkmcnt(0)" ::: "memory");
    short8 ap = *(const short8*)&pb[m*40 + qd*8];
    short8 bv;
    #pragma unroll
    for (int j = 0; j < 8; ++j) bv[j] = (short)vbuf[(kb + qd*8 + j)*20 + m];
    oacc = __builtin_amdgcn_mfma_f32_16x16x32_bf16(ap, bv, oacc, 0, 0, 0);
  }

  float lp[4] = {lp0, lp1, lp2, lp3};
  #pragma unroll
  for (int reg = 0; reg < 4; ++reg) {
    float l = lp[reg];
    l += __shfl_xor(l, 1); l += __shfl_xor(l, 2);
    l += __shfl_xor(l, 4); l += __shfl_xor(l, 8);
    float ov = oacc[reg] / l;
    att[(size_t)(b*SS + qr0 + qd*4 + reg)*128 + h*16 + m] = f2bf(ov);
  }
}

// ==================== driver ====================
extern "C" void kernel_launch(void* const* d_in, const int* in_sizes, int n_in,
                              void* d_out, int out_size, void* d_ws, size_t ws_size,
                              hipStream_t stream) {
  const float* x        = (const float*)d_in[0];
  const int*   mask     = (const int*)d_in[1];
  const float* ln_scale = (const float*)d_in[2];
  const float* ln_bias  = (const float*)d_in[3];
  const float* dw_w     = (const float*)d_in[4];
  const float* dw_b     = (const float*)d_in[5];
  const float* pw_w     = (const float*)d_in[6];
  const float* pw_b     = (const float*)d_in[7];
  const float* Wq       = (const float*)d_in[8];
  const float* Wk       = (const float*)d_in[9];
  const float* Wv       = (const float*)d_in[10];
  const float* Wo       = (const float*)d_in[11];
  const float* att_bias = (const float*)d_in[12];
  const float* f1_w     = (const float*)d_in[13];
  const float* f1_b     = (const float*)d_in[14];
  const float* f2_w     = (const float*)d_in[15];
  const float* f2_b     = (const float*)d_in[16];
  float* out = (float*)d_out;

  ushort* wall    = (ushort*)d_ws;
  ushort* pw_bf   = wall;
  ushort* wqkv_bf = wall + 65536;
  ushort* wo_bf   = wall + 114688;
  ushort* f1_bf   = wall + 131072;
  ushort* f2_bf   = wall + 147456;
  ushort* qkvbuf  = wall + 163840;                       // [N][384] bf16
  ushort* attbuf  = qkvbuf + (size_t)NN*384;             // [N][128] bf16
  ushort* ybuf    = attbuf + (size_t)NN*128;             // [N][128] bf16

  hipLaunchKernelGGL(prep_kernel, dim3(640), dim3(256), 0, stream,
                     pw_w, Wq, Wk, Wv, Wo, f1_w, f2_w, wall);

  hipLaunchKernelGGL((conv_fused_kernel<1>), dim3(NN/16), dim3(256), 0, stream,
                     x, pw_bf, ln_scale, ln_bias, dw_w, dw_b, pw_b, out);
  for (int i = 1; i < NCONV; ++i) {
    hipLaunchKernelGGL((conv_fused_kernel<0>), dim3(NN/16), dim3(256), 0, stream,
                       out, pw_bf + i*16384, ln_scale + i*128, ln_bias + i*128,
                       dw_w + i*896, dw_b + i*128, pw_b + i*128, out);
  }

  // LN + QKV projection -> qkvbuf bf16 [N][384]
  hipLaunchKernelGGL((mm16_kernel<1,0,2,0,1>), dim3(NN/16, 3), dim3(256), 0, stream,
                     out, nullptr, wqkv_bf, ln_scale + 4*128, ln_bias + 4*128,
                     att_bias, nullptr, nullptr, qkvbuf, 384);

  hipLaunchKernelGGL(attn_mfma_kernel, dim3(BB*HH*8), dim3(256), 0, stream,
                     qkvbuf, mask, attbuf);

  // output projection + residual
  hipLaunchKernelGGL((mm16_kernel<0,0,2,1,0>), dim3(NN/16, 1), dim3(256), 0, stream,
                     nullptr, attbuf, wo_bf, nullptr, nullptr,
                     att_bias, out, out, nullptr, 128);

  // FFN
  hipLaunchKernelGGL((mm16_kernel<1,1,1,0,1>), dim3(NN/16, 1), dim3(256), 0, stream,
                     out, nullptr, f1_bf, ln_scale + 5*128, ln_bias + 5*128,
                     f1_b, nullptr, nullptr, ybuf, 128);
  hipLaunchKernelGGL((mm16_kernel<0,0,1,1,0>), dim3(NN/16, 1), dim3(256), 0, stream,
                     nullptr, ybuf, f2_bf, nullptr, nullptr,
                     f2_b, out, out, nullptr, 128);
}